// Round 6
// baseline (2196.528 us; speedup 1.0000x reference)
//
#include <hip/hip_runtime.h>
#include <stdint.h>

typedef unsigned short u16;
typedef __attribute__((ext_vector_type(8))) short short8;
typedef __attribute__((ext_vector_type(16))) float f32x16;

__device__ __forceinline__ u16 f2bf(float f) {
  uint32_t u = __builtin_bit_cast(uint32_t, f);
  u += 0x7fffu + ((u >> 16) & 1u);
  return (u16)(u >> 16);
}

__device__ __forceinline__ void gld16(const void* g, void* l) {
  __builtin_amdgcn_global_load_lds(
      (const __attribute__((address_space(1))) void*)g,
      (__attribute__((address_space(3))) void*)l, 16, 0, 0);
}

__device__ __forceinline__ void waitv(int n) {
  switch (n) {
    case 0: asm volatile("s_waitcnt vmcnt(0)" ::: "memory"); break;
    case 1: asm volatile("s_waitcnt vmcnt(1)" ::: "memory"); break;
    case 2: asm volatile("s_waitcnt vmcnt(2)" ::: "memory"); break;
    case 3: asm volatile("s_waitcnt vmcnt(3)" ::: "memory"); break;
    case 4: asm volatile("s_waitcnt vmcnt(4)" ::: "memory"); break;
    case 5: asm volatile("s_waitcnt vmcnt(5)" ::: "memory"); break;
    case 6: asm volatile("s_waitcnt vmcnt(6)" ::: "memory"); break;
    default: asm volatile("s_waitcnt vmcnt(7)" ::: "memory"); break;
  }
}

// ---------------------------------------------------------------------------
// Weight prep (MFMA-fragment order, 32x32 tiles).
// wA: [cb 8][tap 9][kb 8][nl 192][kk 32]; nl = nh*96 + p*32 + gp*16 + cl
//   c = cb*32 + nh*16 + cl; gp=0: o=p*256+c, W = w_ih[:, :256] - w_ih[:,256:]/5
//                           gp=1: o=p*256+c, W = w_hh
// wS: [cb 8][tap 9][kb 8][nl 96][kk 32]; nl = p*32 + cl; o = p*256 + cb*32+cl
//   W = w_ih[:,256:512]/5
// ---------------------------------------------------------------------------
__global__ __launch_bounds__(256) void k_wprep(const float* __restrict__ w_ih,
                                               const float* __restrict__ w_hh,
                                               u16* __restrict__ wA,
                                               u16* __restrict__ wS) {
  const int NA = 8*9*8*192*32;
  const int NS = 8*9*8*96*32;
  for (int idx = blockIdx.x*blockDim.x + threadIdx.x; idx < NA + NS;
       idx += gridDim.x*blockDim.x) {
    if (idx < NA) {
      int kk = idx & 31; int t = idx >> 5;
      int nl = t % 192; t /= 192;
      int kb = t & 7; t >>= 3;
      int tap = t % 9; int cb = t / 9;
      int nh = nl / 96; int r2 = nl % 96;
      int p = r2 >> 5, gp = (r2 >> 4) & 1, cl = r2 & 15;
      int c = cb*32 + nh*16 + cl, ci = kb*32 + kk;
      int o = p*256 + c;
      float v;
      if (gp == 0)
        v = w_ih[(o*512 + ci)*9 + tap] - 0.2f * w_ih[(o*512 + 256 + ci)*9 + tap];
      else
        v = w_hh[(o*256 + ci)*9 + tap];
      wA[idx] = f2bf(v);
    } else {
      int j = idx - NA;
      int kk = j & 31; int t = j >> 5;
      int nl = t % 96; t /= 96;
      int kb = t & 7; t >>= 3;
      int tap = t % 9; int cb = t / 9;
      int p = nl >> 5, cl = nl & 31;
      int o = p*256 + cb*32 + cl, ci = kb*32 + kk;
      wS[j] = f2bf(0.2f * w_ih[(o*512 + 256 + ci)*9 + tap]);
    }
  }
}

// ---------------------------------------------------------------------------
// NCHW fp32 master -> NHWC bf16 per-agent x, and per-batch agent-sum s.
// ---------------------------------------------------------------------------
__global__ __launch_bounds__(256) void k_xform(const float* __restrict__ src,
                                               u16* __restrict__ xbf,
                                               u16* __restrict__ sbf) {
  __shared__ float lds[32][33];
  const int t = threadIdx.x;
  const int tx = t & 31, ty = t >> 5;
  const int p0 = blockIdx.x*32, c0 = blockIdx.y*32, b = blockIdx.z;
  const int po = t >> 3, co = (t & 7)*4;
  float ss[4] = {0.f,0.f,0.f,0.f};
  for (int a = 0; a < 6; ++a) {
    const int im = b*6 + a;
    const float* sp = src + ((size_t)im*256 + c0)*1024 + p0;
    #pragma unroll
    for (int k = 0; k < 4; ++k) {
      float v = sp[(size_t)(ty + 8*k)*1024 + tx];
      ss[k] += v;
      lds[ty + 8*k][tx] = v;
    }
    __syncthreads();
    ushort4 pk = make_ushort4(f2bf(lds[co+0][po]), f2bf(lds[co+1][po]),
                              f2bf(lds[co+2][po]), f2bf(lds[co+3][po]));
    *(ushort4*)(xbf + ((size_t)im*1024 + p0+po)*256 + c0 + co) = pk;
    __syncthreads();
  }
  #pragma unroll
  for (int k = 0; k < 4; ++k) lds[ty + 8*k][tx] = ss[k];
  __syncthreads();
  ushort4 pk = make_ushort4(f2bf(lds[co+0][po]), f2bf(lds[co+1][po]),
                            f2bf(lds[co+2][po]), f2bf(lds[co+3][po]));
  *(ushort4*)(sbf + ((size_t)b*1024 + p0+po)*256 + c0 + co) = pk;
}

// ---------------------------------------------------------------------------
// Implicit-GEMM 3x3 conv on mfma_f32_32x32x16_bf16.
// 8 waves = (8/NH) row-groups x NH n-halves; wave = MT row-tiles x 3 N-tiles.
// B triple-buffered per tap (staged 2 ahead), A slab per kb (staged at tap 6),
// counted vmcnt + raw s_barrier. OOB handled by zero-block address select.
// GATES: fused GRU epilogue via lane^16 ds_swizzle gate-pair exchange.
// ---------------------------------------------------------------------------
template<int MT, int NH, bool GATES>
__global__ __launch_bounds__(512, 2)
void k_conv32(const u16* __restrict__ xin, const u16* __restrict__ wpre,
              float* __restrict__ gsbuf,
              const float* __restrict__ b_ih, const float* __restrict__ b_hh,
              const float* __restrict__ h_in, float* __restrict__ h_out) {
  constexpr int RGC   = 8 / NH;
  constexpr int ROWS  = MT * RGC;        // rows per block
  constexpr int MTC   = 32 / ROWS;       // row-blocks per image
  constexpr int NBLK  = 96 * NH;         // N per block
  constexpr int SLABR = ROWS + 2;
  constexpr int SLABSZ = SLABR * 1024;   // u16 per A buffer
  constexpr int BBSZ   = NBLK * 32;      // u16 per B tap-buffer
  constexpr int ZOFF   = 2*SLABSZ + 3*BBSZ;
  constexpr int TOTA   = SLABR * 128;    // 16B loads per A stage
  constexpr int TOTB   = NBLK * 4;       // 16B loads per B stage
  __shared__ __align__(16) u16 L[ZOFF + 64];

  const int tid = threadIdx.x;
  const int l   = tid & 63;
  const int w   = tid >> 6;
  const int rg  = w / NH;
  const int nh  = w % NH;
  const int colc = l & 31;     // A-row (image col) / B-col (n) lane index
  const int kch  = l >> 5;     // k-chunk parity

  int bid = blockIdx.x;
  const int cb  = bid & 7;
  const int rest = bid >> 3;
  const int mt  = rest % MTC;
  const int img = rest / MTC;
  const int h0  = mt * ROWS;

  const u16* srcimg = xin + (size_t)img * (1024*256);

  const int trf = __builtin_amdgcn_readfirstlane(tid);
  const int myA = TOTA/512 + ((trf < (TOTA % 512)) ? 1 : 0);
  const int myB = TOTB/512 + ((trf < (TOTB % 512)) ? 1 : 0);

  auto stageA = [&](int kb, int sbuf) {
    #pragma unroll
    for (int ii = 0; ii < (TOTA + 511)/512; ++ii) {
      int i = ii*512 + tid;
      if (i < TOTA) {
        int p = i >> 2, ck = i & 3;
        int pr = p >> 5, pc = p & 31;
        int gr = h0 - 1 + pr;
        gr = gr < 0 ? 0 : (gr > 31 ? 31 : gr);
        int sck = ck ^ ((pc >> 1) & 3);
        gld16(srcimg + (gr*32 + pc)*256 + kb*32 + sck*8, &L[sbuf*SLABSZ + i*8]);
      }
    }
  };
  auto stageB = [&](int kb, int tap, int bb) {
    const u16* wb = wpre + (size_t)((cb*9 + tap)*8 + kb) * BBSZ;
    #pragma unroll
    for (int ii = 0; ii < (TOTB + 511)/512; ++ii) {
      int i = ii*512 + tid;
      if (i < TOTB) {
        int nl = i >> 2, ck = i & 3;
        int sck = ck ^ ((nl >> 1) & 3);
        gld16(wb + nl*32 + sck*8, &L[2*SLABSZ + bb*BBSZ + i*8]);
      }
    }
  };

  f32x16 acc[MT][3];
  #pragma unroll
  for (int mi = 0; mi < MT; ++mi)
    #pragma unroll
    for (int t = 0; t < 3; ++t)
      #pragma unroll
      for (int e = 0; e < 16; ++e) acc[mi][t][e] = 0.f;

  if (tid < 64) L[ZOFF + tid] = 0;        // zero block for OOB fragments
  stageA(0, 0);
  stageB(0, 0, 0);
  stageB(0, 1, 1);
  asm volatile("s_waitcnt lgkmcnt(0)" ::: "memory");

  const int bkey = (colc >> 1) & 3;
  const int bln  = (nh*96 + colc) * 32;

  for (int kb = 0; kb < 8; ++kb) {
    const int sb = kb & 1;
    #pragma unroll
    for (int tap = 0; tap < 9; ++tap) {
      if (kb == 7 && tap == 8) waitv(0);
      else if (tap == 7 && kb < 7) waitv(myA + myB);
      else waitv(myB);
      __builtin_amdgcn_s_barrier();
      __builtin_amdgcn_sched_barrier(0);

      if (tap == 6 && kb < 7) stageA(kb+1, sb^1);
      if (kb < 7 || tap < 7) {
        const int kb2 = (tap < 7) ? kb : kb+1;
        const int tp2 = (tap < 7) ? tap+2 : tap-7;
        stageB(kb2, tp2, (tap+2) % 3);
      }

      const int dy = tap/3, dx = tap%3;
      const int cc = colc + dx - 1;
      const bool colok = (unsigned)cc < 32u;
      const int akey = (cc >> 1) & 3;
      const int cc32 = cc * 32;
      const int sbb = sb * SLABSZ;
      const u16* bp0 = &L[2*SLABSZ + (tap%3)*BBSZ + bln];

      __builtin_amdgcn_s_setprio(1);
      #pragma unroll
      for (int ks = 0; ks < 2; ++ks) {
        const int c2 = ks*2 + kch;
        const int ach = (c2 ^ akey) * 8;
        const int bch = (c2 ^ bkey) * 8;
        short8 b0 = *(const short8*)(bp0 + bch);
        short8 b1 = *(const short8*)(bp0 + bch + 1024);
        short8 b2 = *(const short8*)(bp0 + bch + 2048);
        #pragma unroll
        for (int mi = 0; mi < MT; ++mi) {
          const int rr = rg*MT + mi + dy;        // slab row
          const int grow = h0 + rr - 1;          // image row (wave-uniform)
          const bool ok = ((unsigned)grow < 32u) && colok;
          int aidx = sbb + rr*1024 + cc32 + ach;
          aidx = ok ? aidx : ZOFF;
          short8 av = *(const short8*)&L[aidx];
          acc[mi][0] = __builtin_amdgcn_mfma_f32_32x32x16_bf16(av, b0, acc[mi][0], 0, 0, 0);
          acc[mi][1] = __builtin_amdgcn_mfma_f32_32x32x16_bf16(av, b1, acc[mi][1], 0, 0, 0);
          acc[mi][2] = __builtin_amdgcn_mfma_f32_32x32x16_bf16(av, b2, acc[mi][2], 0, 0, 0);
        }
      }
      __builtin_amdgcn_s_setprio(0);
    }
  }

  if constexpr (GATES) {
    // C/D: col = lane&31 = gp*16+cl, row m = (reg&3)+8*(reg>>2)+4*(lane>>5).
    // gp=0 lane owns i-gates, gp=1 owns h-gates of channel cl; exchange via
    // ds_swizzle lane^16 so each lane computes 8 rows (regs gp*8..gp*8+7).
    const int gp2 = (l >> 4) & 1;
    const int cl  = l & 15;
    const int hx  = l >> 5;
    const int cch = cb*32 + nh*16 + cl;
    const int bat = img / 6;
    float bI[3], bH[3];
    #pragma unroll
    for (int p = 0; p < 3; ++p) { bI[p] = b_ih[p*256 + cch]; bH[p] = b_hh[p*256 + cch]; }
    const float* gs0 = gsbuf + ((size_t)(bat*3+0)*256 + cch)*1024;
    const float* gs1 = gsbuf + ((size_t)(bat*3+1)*256 + cch)*1024;
    const float* gs2 = gsbuf + ((size_t)(bat*3+2)*256 + cch)*1024;
    const float* hp  = h_in  + ((size_t)img*256 + cch)*1024;
    float*       op  = h_out + ((size_t)img*256 + cch)*1024;
    #pragma unroll
    for (int mi = 0; mi < MT; ++mi) {
      const int R = h0 + rg*MT + mi;
      const int px0 = R*32 + gp2*16 + hx*4;
      float4 Ga0 = *(const float4*)(gs0 + px0), Gb0 = *(const float4*)(gs0 + px0 + 8);
      float4 Ga1 = *(const float4*)(gs1 + px0), Gb1 = *(const float4*)(gs1 + px0 + 8);
      float4 Ga2 = *(const float4*)(gs2 + px0), Gb2 = *(const float4*)(gs2 + px0 + 8);
      float4 Ha  = *(const float4*)(hp + px0),  Hb  = *(const float4*)(hp + px0 + 8);
      float4 Oa, Ob;
      #pragma unroll
      for (int j = 0; j < 8; ++j) {
        const int jj = j & 3;
        float iv[3], hv[3];
        #pragma unroll
        for (int p = 0; p < 3; ++p) {
          float own = gp2 ? acc[mi][p][8+j] : acc[mi][p][j];
          float snd = gp2 ? acc[mi][p][j]   : acc[mi][p][8+j];
          int gi = __builtin_amdgcn_ds_swizzle(__builtin_bit_cast(int, snd), 0x401F);
          float got = __builtin_bit_cast(float, gi);
          iv[p] = gp2 ? got : own;
          hv[p] = gp2 ? own : got;
        }
        float g0 = (j < 4) ? (&Ga0.x)[jj] : (&Gb0.x)[jj];
        float g1 = (j < 4) ? (&Ga1.x)[jj] : (&Gb1.x)[jj];
        float g2 = (j < 4) ? (&Ga2.x)[jj] : (&Gb2.x)[jj];
        float hold = (j < 4) ? (&Ha.x)[jj] : (&Hb.x)[jj];
        float ir  = iv[0] + g0 + bI[0];
        float ii  = iv[1] + g1 + bI[1];
        float inn = iv[2] + g2 + bI[2];
        float hr  = hv[0] + bH[0];
        float hi2 = hv[1] + bH[1];
        float hn  = hv[2] + bH[2];
        float rgt = 1.f/(1.f + __expf(-(ir+hr)));
        float igt = 1.f/(1.f + __expf(-(ii+hi2)));
        float nx = inn + rgt*hn;
        nx = nx > 20.f ? 20.f : (nx < -20.f ? -20.f : nx);
        float e2 = __expf(-2.f*nx);
        float ng = (1.f - e2)/(1.f + e2);
        float hy = ng + igt*(hold - ng);
        if (j < 4) (&Oa.x)[jj] = hy; else (&Ob.x)[jj] = hy;
      }
      *(float4*)(op + px0) = Oa;
      *(float4*)(op + px0 + 8) = Ob;
    }
  } else {
    const int ch = cb*32 + colc;
    const int hx = l >> 5;
    #pragma unroll
    for (int mi = 0; mi < MT; ++mi) {
      const int R = h0 + rg*MT + mi;
      #pragma unroll
      for (int p = 0; p < 3; ++p) {
        float* gd = gsbuf + ((size_t)(img*3+p)*256 + ch)*1024;
        #pragma unroll
        for (int grp = 0; grp < 4; ++grp) {
          float4 v = make_float4(acc[mi][p][grp*4+0], acc[mi][p][grp*4+1],
                                 acc[mi][p][grp*4+2], acc[mi][p][grp*4+3]);
          *(float4*)(gd + R*32 + grp*8 + hx*4) = v;
        }
      }
    }
  }
}

// ---------------------------------------------------------------------------
extern "C" void kernel_launch(void* const* d_in, const int* in_sizes, int n_in,
                              void* d_out, int out_size, void* d_ws, size_t ws_size,
                              hipStream_t stream) {
  const float* x    = (const float*)d_in[0];
  const float* w_ih = (const float*)d_in[1];
  const float* w_hh = (const float*)d_in[2];
  const float* b_ih = (const float*)d_in[3];
  const float* b_hh = (const float*)d_in[4];
  float* out = (float*)d_out;

  char* ws = (char*)d_ws;
  float* m0  = (float*)(ws);                 // master scratch (iter-1 output)
  u16*  xbf  = (u16*)(ws + 50331648);        // x bf16 NHWC
  u16*  sbf  = (u16*)(ws + 75497472);        // s bf16 NHWC
  float* gsb = (float*)(ws + 79691776);      // gs fp32 [b][p][ch][px]
  u16*  wA   = (u16*)(ws + 104857600);
  u16*  wS   = (u16*)(ws + 111935488);

  k_wprep<<<2048, 256, 0, stream>>>(w_ih, w_hh, wA, wS);

  for (int it = 0; it < 3; ++it) {
    const float* src = (it == 0) ? x : (it == 1 ? out : m0);
    float* dst = (it == 1) ? m0 : out;
    k_xform<<<dim3(32, 8, 8), 256, 0, stream>>>(src, xbf, sbf);
    k_conv32<1, 1, false><<<256, 512, 0, stream>>>(sbf, wS, gsb,
                                                   nullptr, nullptr, nullptr, nullptr);
    k_conv32<4, 2, true><<<768, 512, 0, stream>>>(xbf, wA, gsb,
                                                  b_ih, b_hh, src, dst);
  }
}

// Round 8
// 1859.060 us; speedup vs baseline: 1.1815x; 1.1815x over previous
//
#include <hip/hip_runtime.h>
#include <stdint.h>

typedef unsigned short u16;
typedef __attribute__((ext_vector_type(8))) short short8;
typedef __attribute__((ext_vector_type(4))) float f32x4;

__device__ __forceinline__ u16 f2bf(float f) {
  uint32_t u = __builtin_bit_cast(uint32_t, f);
  u += 0x7fffu + ((u >> 16) & 1u);
  return (u16)(u >> 16);
}

__device__ __forceinline__ void gld16(const void* g, void* l) {
  __builtin_amdgcn_global_load_lds(
      (const __attribute__((address_space(1))) void*)g,
      (__attribute__((address_space(3))) void*)l, 16, 0, 0);
}

// wave-uniform counted vmcnt wait
__device__ __forceinline__ void waitv(int n) {
  switch (n) {
    case 0: asm volatile("s_waitcnt vmcnt(0)" ::: "memory"); break;
    case 1: asm volatile("s_waitcnt vmcnt(1)" ::: "memory"); break;
    case 2: asm volatile("s_waitcnt vmcnt(2)" ::: "memory"); break;
    case 3: asm volatile("s_waitcnt vmcnt(3)" ::: "memory"); break;
    case 4: asm volatile("s_waitcnt vmcnt(4)" ::: "memory"); break;
    case 5: asm volatile("s_waitcnt vmcnt(5)" ::: "memory"); break;
    default: asm volatile("s_waitcnt vmcnt(6)" ::: "memory"); break;
  }
}

// ---------------------------------------------------------------------------
// Weight prep: MFMA-fragment-ordered bf16 weights (16x16 layout).
// wA: [cb 8][tap 9][kb 8][nl 192][kk 32], nl = q*96 + g*16 + cl:
//     c = cb*32 + q*16 + cl
//     g<3 : o = g*256 + c,     W = w_ih[:, :256] - w_ih[:,256:512]/5
//     g>=3: o = (g-3)*256 + c, W = w_hh
// wS: [cb 8][tap 9][kb 8][nl 96][kk 32], o = cb*96 + nl, W = w_ih[:,256:512]/5
// ---------------------------------------------------------------------------
__global__ __launch_bounds__(256) void k_wprep(const float* __restrict__ w_ih,
                                               const float* __restrict__ w_hh,
                                               u16* __restrict__ wA,
                                               u16* __restrict__ wS) {
  const int NA = 8*9*8*192*32;
  const int NS = 8*9*8*96*32;
  for (int idx = blockIdx.x*blockDim.x + threadIdx.x; idx < NA + NS;
       idx += gridDim.x*blockDim.x) {
    if (idx < NA) {
      int kk = idx & 31; int t = idx >> 5;
      int nl = t % 192; t /= 192;
      int kb = t & 7; t >>= 3;
      int tap = t % 9; int cb = t / 9;
      int qq = nl / 96; int rr = nl % 96;
      int g = rr >> 4, cl = rr & 15;
      int c = cb*32 + qq*16 + cl, ci = kb*32 + kk;
      float v;
      if (g < 3) {
        int o = g*256 + c;
        v = w_ih[(o*512 + ci)*9 + tap] - 0.2f * w_ih[(o*512 + 256 + ci)*9 + tap];
      } else {
        int o = (g-3)*256 + c;
        v = w_hh[(o*256 + ci)*9 + tap];
      }
      wA[idx] = f2bf(v);
    } else {
      int j = idx - NA;
      int kk = j & 31; int t = j >> 5;
      int nl = t % 96; t /= 96;
      int kb = t & 7; t >>= 3;
      int tap = t % 9; int cb = t / 9;
      int o = cb*96 + nl, ci = kb*32 + kk;
      wS[j] = f2bf(0.2f * w_ih[(o*512 + 256 + ci)*9 + tap]);
    }
  }
}

// ---------------------------------------------------------------------------
// NCHW fp32 master -> NHWC bf16 per-agent x, and per-batch agent-sum s.
// ---------------------------------------------------------------------------
__global__ __launch_bounds__(256) void k_xform(const float* __restrict__ src,
                                               u16* __restrict__ xbf,
                                               u16* __restrict__ sbf) {
  __shared__ float lds[32][33];
  const int t = threadIdx.x;
  const int tx = t & 31, ty = t >> 5;
  const int p0 = blockIdx.x*32, c0 = blockIdx.y*32, b = blockIdx.z;
  const int po = t >> 3, co = (t & 7)*4;
  float ss[4] = {0.f,0.f,0.f,0.f};
  for (int a = 0; a < 6; ++a) {
    const int im = b*6 + a;
    const float* sp = src + ((size_t)im*256 + c0)*1024 + p0;
    #pragma unroll
    for (int k = 0; k < 4; ++k) {
      float v = sp[(size_t)(ty + 8*k)*1024 + tx];
      ss[k] += v;
      lds[ty + 8*k][tx] = v;
    }
    __syncthreads();
    ushort4 pk = make_ushort4(f2bf(lds[co+0][po]), f2bf(lds[co+1][po]),
                              f2bf(lds[co+2][po]), f2bf(lds[co+3][po]));
    *(ushort4*)(xbf + ((size_t)im*1024 + p0+po)*256 + c0 + co) = pk;
    __syncthreads();
  }
  #pragma unroll
  for (int k = 0; k < 4; ++k) lds[ty + 8*k][tx] = ss[k];
  __syncthreads();
  ushort4 pk = make_ushort4(f2bf(lds[co+0][po]), f2bf(lds[co+1][po]),
                            f2bf(lds[co+2][po]), f2bf(lds[co+3][po]));
  *(ushort4*)(sbf + ((size_t)b*1024 + p0+po)*256 + c0 + co) = pk;
}

// ---------------------------------------------------------------------------
// Implicit-GEMM 3x3 conv, 16x16x32 MFMA, 8 waves = 4 row-groups x 2 N-halves.
// Pipeline: B 4-deep (staged 3 taps ahead), A slab 2-deep (staged at tap 6);
// counted vmcnt + raw s_barrier; REGISTER prefetch of tap t+1's A/B fragments
// issued before tap t's MFMA cluster so ds_read overlaps MFMA.
// GATES: fused GRU epilogue (GF==6). else: writes gsbuf[img][n][pix].
// ---------------------------------------------------------------------------
template<int GF, bool GATES>
__global__ __launch_bounds__(512, 2)
void k_conv(const u16* __restrict__ xin, const u16* __restrict__ wpre,
            float* __restrict__ gsbuf,
            const float* __restrict__ b_ih, const float* __restrict__ b_hh,
            const float* __restrict__ h_in, float* __restrict__ h_out) {
  constexpr int NT   = 512;
  constexpr int SLAB = 10*32*32;        // u16 per A buffer
  constexpr int BN   = 2*GF*16*32;      // u16 per B tap-buffer
  constexpr int TOTA = 10*128;          // 16B loads per A stage
  constexpr int TOTB = BN/8;            // 16B loads per B stage
  __shared__ __align__(16) u16 slab[2][SLAB];
  __shared__ __align__(16) u16 bbuf[4][BN];

  const int tid = threadIdx.x;
  const int l  = tid & 63;
  const int w  = tid >> 6;
  const int lx = l & 15;
  const int lk = l >> 4;
  const int rg = w >> 1;
  const int q  = w & 1;

  int bid = blockIdx.x;
  const int cb = bid & 7; bid >>= 3;
  const int mt = bid & 3;
  const int img = bid >> 2;
  const int h0 = mt * 8;

  const u16* srcimg = xin + (size_t)img * (1024*256);

  const int trf = __builtin_amdgcn_readfirstlane(tid);
  const int myB = TOTB/NT + ((trf < (TOTB % NT)) ? 1 : 0);
  const int myA = TOTA/NT + ((trf < (TOTA % NT)) ? 1 : 0);

  auto stageA = [&](int kb, int sbuf) {
    #pragma unroll
    for (int ii = 0; ii < (TOTA + NT - 1)/NT; ++ii) {
      int i = ii*NT + tid;
      if (i < TOTA) {
        int p = i >> 2, ck = i & 3;
        int pr = p >> 5, pc = p & 31;
        int gr = h0 - 1 + pr;
        gr = gr < 0 ? 0 : (gr > 31 ? 31 : gr);
        int sck = ck ^ ((p >> 1) & 3);
        gld16(srcimg + (gr*32 + pc)*256 + kb*32 + sck*8, &slab[sbuf][i*8]);
      }
    }
  };
  auto stageB = [&](int kb, int tap, int bb) {
    const u16* wb = wpre + (size_t)((cb*9 + tap)*8 + kb) * BN;
    #pragma unroll
    for (int ii = 0; ii < (TOTB + NT - 1)/NT; ++ii) {
      int i = ii*NT + tid;
      if (i < TOTB) {
        int nl = i >> 2, ck = i & 3;
        int sck = ck ^ ((nl >> 1) & 3);
        gld16(wb + nl*32 + sck*8, &bbuf[bb][i*8]);
      }
    }
  };

  // register fragment loads (LDS -> VGPR)
  auto loadA = [&](short8 (&a)[4], int DY, int DX, int ssel) {
    #pragma unroll
    for (int mi = 0; mi < 4; ++mi) {
      const int grow = h0 + rg*2 + (mi>>1) + DY - 1;
      const int cc = (mi&1)*16 + lx + DX - 1;
      const bool ok = (grow >= 0) && (grow < 32) && (cc >= 0) && (cc < 32);
      const int ccc = cc < 0 ? 0 : (cc > 31 ? 31 : cc);
      const int sr = rg*2 + (mi>>1) + DY;
      short8 av = *(const short8*)&slab[ssel][(sr*32 + ccc)*32 + (lk ^ ((ccc >> 1) & 3))*8];
      if (!ok) av = (short8){0,0,0,0,0,0,0,0};
      a[mi] = av;
    }
  };
  auto loadB = [&](short8 (&b)[GF], int bb) {
    const u16* bp = &bbuf[bb][(q*(GF*16) + lx)*32 + (lk ^ ((lx >> 1) & 3))*8];
    #pragma unroll
    for (int g = 0; g < GF; ++g) b[g] = *(const short8*)(bp + g*512);
  };

  f32x4 acc[4][GF];
  #pragma unroll
  for (int mi = 0; mi < 4; ++mi)
    #pragma unroll
    for (int g = 0; g < GF; ++g) acc[mi][g] = (f32x4){0.f,0.f,0.f,0.f};

  short8 a_cur[4], b_cur[GF], a_nxt[4], b_nxt[GF];

  // prologue: stage A0 and B0..B2 (3 deep), wait all but newest, preload tap 0
  stageA(0, 0);
  stageB(0, 0, 0);
  stageB(0, 1, 1);
  stageB(0, 2, 2);
  waitv(myB);
  __builtin_amdgcn_s_barrier();
  loadA(a_cur, 0, 0, 0);
  loadB(b_cur, 0);

  for (int kb = 0; kb < 8; ++kb) {
    const int sb = kb & 1;
    #pragma unroll
    for (int tap = 0; tap < 9; ++tap) {
      // wait: everything except stages issued in the previous tap must be done
      if (tap == 7)      { if (kb < 7) waitv(myA + myB); else waitv(0); }
      else if (tap == 8) { if (kb < 7) waitv(myB);       else waitv(0); }
      else               waitv(myB);
      __builtin_amdgcn_s_barrier();

      if (tap == 6 && kb < 7) stageA(kb+1, sb^1);
      if (kb*9 + tap <= 68) {
        const int kb2 = (tap < 6) ? kb : kb+1;
        const int tp2 = (tap < 6) ? tap+3 : tap-6;
        stageB(kb2, tp2, (kb*9 + tap + 3) & 3);
      }

      // register prefetch of next tap (overlaps this tap's MFMA cluster)
      if (tap < 8) {
        loadA(a_nxt, (tap+1)/3, (tap+1)%3, sb);
        loadB(b_nxt, (kb*9 + tap + 1) & 3);
      } else if (kb < 7) {
        loadA(a_nxt, 0, 0, sb^1);
        loadB(b_nxt, (kb*9 + tap + 1) & 3);
      }

      __builtin_amdgcn_s_setprio(1);
      #pragma unroll
      for (int g = 0; g < GF; ++g)
        #pragma unroll
        for (int mi = 0; mi < 4; ++mi)
          acc[mi][g] = __builtin_amdgcn_mfma_f32_16x16x32_bf16(a_cur[mi], b_cur[g], acc[mi][g], 0, 0, 0);
      __builtin_amdgcn_s_setprio(0);

      #pragma unroll
      for (int mi = 0; mi < 4; ++mi) a_cur[mi] = a_nxt[mi];
      #pragma unroll
      for (int g = 0; g < GF; ++g)  b_cur[g] = b_nxt[g];
    }
  }

  if constexpr (GATES) {
    const int b = img / 6;
    const int c = cb*32 + q*16 + lx;
    const float bir = b_ih[c],  bii = b_ih[256+c], bin_ = b_ih[512+c];
    const float bhr = b_hh[c],  bhi = b_hh[256+c], bhn  = b_hh[512+c];
    const float* gs0 = gsbuf + ((size_t)(b*3+0)*256 + c)*1024;
    const float* gs1 = gsbuf + ((size_t)(b*3+1)*256 + c)*1024;
    const float* gs2 = gsbuf + ((size_t)(b*3+2)*256 + c)*1024;
    const float* hp  = h_in  + ((size_t)img*256 + c)*1024;
    float*       op  = h_out + ((size_t)img*256 + c)*1024;
    #pragma unroll
    for (int mi = 0; mi < 4; ++mi) {
      const int R = h0 + rg*2 + (mi>>1);
      const int pix = R*32 + (mi&1)*16 + lk*4;
      float4 v0 = *(const float4*)(gs0 + pix);
      float4 v1 = *(const float4*)(gs1 + pix);
      float4 v2 = *(const float4*)(gs2 + pix);
      float4 hv = *(const float4*)(hp + pix);
      float4 o;
      #pragma unroll
      for (int r = 0; r < 4; ++r) {
        float ir  = acc[mi][0][r] + (&v0.x)[r] + bir;
        float ii  = acc[mi][1][r] + (&v1.x)[r] + bii;
        float inn = acc[mi][2][r] + (&v2.x)[r] + bin_;
        float hr  = acc[mi][3][r] + bhr;
        float hi2 = acc[mi][4][r] + bhi;
        float hn  = acc[mi][5][r] + bhn;
        float rgt = 1.f/(1.f + __expf(-(ir+hr)));
        float igt = 1.f/(1.f + __expf(-(ii+hi2)));
        float nx = inn + rgt*hn;
        nx = nx > 20.f ? 20.f : (nx < -20.f ? -20.f : nx);
        float e2 = __expf(-2.f*nx);
        float ng = (1.f - e2)/(1.f + e2);
        (&o.x)[r] = ng + igt*((&hv.x)[r] - ng);
      }
      *(float4*)(op + pix) = o;
    }
  } else {
    #pragma unroll
    for (int g = 0; g < GF; ++g) {
      const int n = cb*(2*GF*16) + q*(GF*16) + g*16 + lx;
      float* gp = gsbuf + ((size_t)img*768 + n)*1024;
      #pragma unroll
      for (int mi = 0; mi < 4; ++mi) {
        const int R = h0 + rg*2 + (mi>>1);
        const int pix = R*32 + (mi&1)*16 + lk*4;
        *(float4*)(gp + pix) = make_float4(acc[mi][g][0], acc[mi][g][1],
                                           acc[mi][g][2], acc[mi][g][3]);
      }
    }
  }
}

// ---------------------------------------------------------------------------
extern "C" void kernel_launch(void* const* d_in, const int* in_sizes, int n_in,
                              void* d_out, int out_size, void* d_ws, size_t ws_size,
                              hipStream_t stream) {
  const float* x    = (const float*)d_in[0];
  const float* w_ih = (const float*)d_in[1];
  const float* w_hh = (const float*)d_in[2];
  const float* b_ih = (const float*)d_in[3];
  const float* b_hh = (const float*)d_in[4];
  float* out = (float*)d_out;

  char* ws = (char*)d_ws;
  float* m0  = (float*)(ws);                 // master scratch (iter-1 output)
  u16*  xbf  = (u16*)(ws + 50331648);        // x bf16 NHWC
  u16*  sbf  = (u16*)(ws + 75497472);        // s bf16 NHWC
  float* gsb = (float*)(ws + 79691776);      // gs fp32
  u16*  wA   = (u16*)(ws + 104857600);
  u16*  wS   = (u16*)(ws + 111935488);

  k_wprep<<<2048, 256, 0, stream>>>(w_ih, w_hh, wA, wS);

  for (int it = 0; it < 3; ++it) {
    const float* src = (it == 0) ? x : (it == 1 ? out : m0);
    float* dst = (it == 1) ? m0 : out;
    k_xform<<<dim3(32, 8, 8), 256, 0, stream>>>(src, xbf, sbf);
    k_conv<3, false><<<256, 512, 0, stream>>>(sbf, wS, gsb,
                                              nullptr, nullptr, nullptr, nullptr);
    k_conv<6, true><<<1536, 512, 0, stream>>>(xbf, wA, gsb,
                                              b_ih, b_hh, src, dst);
  }
}

// Round 9
// 1318.381 us; speedup vs baseline: 1.6661x; 1.4101x over previous
//
#include <hip/hip_runtime.h>
#include <stdint.h>

typedef unsigned short u16;
typedef __attribute__((ext_vector_type(8))) short short8;
typedef __attribute__((ext_vector_type(4))) float f32x4;

__device__ __forceinline__ u16 f2bf(float f) {
  uint32_t u = __builtin_bit_cast(uint32_t, f);
  u += 0x7fffu + ((u >> 16) & 1u);
  return (u16)(u >> 16);
}

__device__ __forceinline__ void gld16(const void* g, void* l) {
  __builtin_amdgcn_global_load_lds(
      (const __attribute__((address_space(1))) void*)g,
      (__attribute__((address_space(3))) void*)l, 16, 0, 0);
}

// wave-uniform counted vmcnt wait
__device__ __forceinline__ void waitv(int n) {
  switch (n) {
    case 0: asm volatile("s_waitcnt vmcnt(0)" ::: "memory"); break;
    case 1: asm volatile("s_waitcnt vmcnt(1)" ::: "memory"); break;
    case 2: asm volatile("s_waitcnt vmcnt(2)" ::: "memory"); break;
    case 3: asm volatile("s_waitcnt vmcnt(3)" ::: "memory"); break;
    case 4: asm volatile("s_waitcnt vmcnt(4)" ::: "memory"); break;
    case 5: asm volatile("s_waitcnt vmcnt(5)" ::: "memory"); break;
    default: asm volatile("s_waitcnt vmcnt(6)" ::: "memory"); break;
  }
}

// ---------------------------------------------------------------------------
// Weight prep: MFMA-fragment-ordered bf16 weights (16x16 layout). Unchanged
// from the 445us baseline.
// wA: [cb 8][tap 9][kb 8][nl 192][kk 32], nl = q*96 + g*16 + cl:
//     c = cb*32 + q*16 + cl
//     g<3 : o = g*256 + c,     W = w_ih[:, :256] - w_ih[:,256:512]/5
//     g>=3: o = (g-3)*256 + c, W = w_hh
// wS: [cb 8][tap 9][kb 8][nl 96][kk 32], o = cb*96 + nl, W = w_ih[:,256:512]/5
// ---------------------------------------------------------------------------
__global__ __launch_bounds__(256) void k_wprep(const float* __restrict__ w_ih,
                                               const float* __restrict__ w_hh,
                                               u16* __restrict__ wA,
                                               u16* __restrict__ wS) {
  const int NA = 8*9*8*192*32;
  const int NS = 8*9*8*96*32;
  for (int idx = blockIdx.x*blockDim.x + threadIdx.x; idx < NA + NS;
       idx += gridDim.x*blockDim.x) {
    if (idx < NA) {
      int kk = idx & 31; int t = idx >> 5;
      int nl = t % 192; t /= 192;
      int kb = t & 7; t >>= 3;
      int tap = t % 9; int cb = t / 9;
      int qq = nl / 96; int rr = nl % 96;
      int g = rr >> 4, cl = rr & 15;
      int c = cb*32 + qq*16 + cl, ci = kb*32 + kk;
      float v;
      if (g < 3) {
        int o = g*256 + c;
        v = w_ih[(o*512 + ci)*9 + tap] - 0.2f * w_ih[(o*512 + 256 + ci)*9 + tap];
      } else {
        int o = (g-3)*256 + c;
        v = w_hh[(o*256 + ci)*9 + tap];
      }
      wA[idx] = f2bf(v);
    } else {
      int j = idx - NA;
      int kk = j & 31; int t = j >> 5;
      int nl = t % 96; t /= 96;
      int kb = t & 7; t >>= 3;
      int tap = t % 9; int cb = t / 9;
      int o = cb*96 + nl, ci = kb*32 + kk;
      wS[j] = f2bf(0.2f * w_ih[(o*512 + 256 + ci)*9 + tap]);
    }
  }
}

// ---------------------------------------------------------------------------
// NCHW fp32 master -> NHWC bf16 per-agent x, and per-batch agent-sum s.
// ---------------------------------------------------------------------------
__global__ __launch_bounds__(256) void k_xform(const float* __restrict__ src,
                                               u16* __restrict__ xbf,
                                               u16* __restrict__ sbf) {
  __shared__ float lds[32][33];
  const int t = threadIdx.x;
  const int tx = t & 31, ty = t >> 5;
  const int p0 = blockIdx.x*32, c0 = blockIdx.y*32, b = blockIdx.z;
  const int po = t >> 3, co = (t & 7)*4;
  float ss[4] = {0.f,0.f,0.f,0.f};
  for (int a = 0; a < 6; ++a) {
    const int im = b*6 + a;
    const float* sp = src + ((size_t)im*256 + c0)*1024 + p0;
    #pragma unroll
    for (int k = 0; k < 4; ++k) {
      float v = sp[(size_t)(ty + 8*k)*1024 + tx];
      ss[k] += v;
      lds[ty + 8*k][tx] = v;
    }
    __syncthreads();
    ushort4 pk = make_ushort4(f2bf(lds[co+0][po]), f2bf(lds[co+1][po]),
                              f2bf(lds[co+2][po]), f2bf(lds[co+3][po]));
    *(ushort4*)(xbf + ((size_t)im*1024 + p0+po)*256 + c0 + co) = pk;
    __syncthreads();
  }
  #pragma unroll
  for (int k = 0; k < 4; ++k) lds[ty + 8*k][tx] = ss[k];
  __syncthreads();
  ushort4 pk = make_ushort4(f2bf(lds[co+0][po]), f2bf(lds[co+1][po]),
                            f2bf(lds[co+2][po]), f2bf(lds[co+3][po]));
  *(ushort4*)(sbf + ((size_t)b*1024 + p0+po)*256 + c0 + co) = pk;
}

// ---------------------------------------------------------------------------
// Implicit-GEMM 3x3 conv, 16x16x32 MFMA.
// NQ=2 (GATES): 8 waves = 4 rows x 2 N-halves; wave = 1 row x 96 N
//   (6 gates x 16 ch in-lane), acc = 2x6 f32x4 = 48 AGPR.
// NQ=1: 8 waves = 8 rows; wave = 1 row x 96 N.
// LDS ~60 KB, __launch_bounds__(512,4) -> 2 blocks/CU = 4 waves/SIMD with
// independent barriers (cross-block MFMA/LDS overlap).
// Schedule: B 3-deep staged 2 taps ahead, A slab 2-deep staged at tap 6,
// counted vmcnt + raw s_barrier (proven 445us pipeline).
// ---------------------------------------------------------------------------
template<int NQ, bool GATES>
__global__ __launch_bounds__(512, 4)
void k_conv(const u16* __restrict__ xin, const u16* __restrict__ wpre,
            float* __restrict__ gsbuf,
            const float* __restrict__ b_ih, const float* __restrict__ b_hh,
            const float* __restrict__ h_in, float* __restrict__ h_out) {
  constexpr int NT    = 512;
  constexpr int RB    = 8 / NQ;          // rows per block
  constexpr int MTC   = 32 / RB;         // row-blocks per image
  constexpr int SLABR = RB + 2;
  constexpr int SLAB  = SLABR*32*32;     // u16 per A buffer
  constexpr int NBLK  = NQ*96;           // N per block
  constexpr int BN    = NBLK*32;         // u16 per B tap-buffer
  constexpr int TOTA  = SLABR*128;       // 16B loads per A stage
  constexpr int TOTB  = BN/8;            // 16B loads per B stage
  __shared__ __align__(16) u16 slab[2][SLAB];
  __shared__ __align__(16) u16 bbuf[3][BN];

  const int tid = threadIdx.x;
  const int l  = tid & 63;
  const int w  = tid >> 6;
  const int lx = l & 15;
  const int lk = l >> 4;
  const int rg = w / NQ;                 // row within block
  const int q  = w % NQ;                 // N-half

  int bid = blockIdx.x;
  const int cb = bid & 7;
  const int rest = bid >> 3;
  const int mt = rest % MTC;
  const int img = rest / MTC;
  const int h0 = mt * RB;

  const u16* srcimg = xin + (size_t)img * (1024*256);

  const int trf = __builtin_amdgcn_readfirstlane(tid);
  const int myB = TOTB/NT + ((trf < (TOTB % NT)) ? 1 : 0);
  const int myA = TOTA/NT + ((trf < (TOTA % NT)) ? 1 : 0);

  auto stageA = [&](int kb, int sbuf) {
    #pragma unroll
    for (int ii = 0; ii < (TOTA + NT - 1)/NT; ++ii) {
      int i = ii*NT + tid;
      if (i < TOTA) {
        int p = i >> 2, ck = i & 3;
        int pr = p >> 5, pc = p & 31;
        int gr = h0 - 1 + pr;
        gr = gr < 0 ? 0 : (gr > 31 ? 31 : gr);
        int sck = ck ^ ((p >> 1) & 3);
        gld16(srcimg + (gr*32 + pc)*256 + kb*32 + sck*8, &slab[sbuf][i*8]);
      }
    }
  };
  auto stageB = [&](int kb, int tap, int bb) {
    const u16* wb = wpre + (size_t)((cb*9 + tap)*8 + kb) * BN;
    #pragma unroll
    for (int ii = 0; ii < (TOTB + NT - 1)/NT; ++ii) {
      int i = ii*NT + tid;
      if (i < TOTB) {
        int nl = i >> 2, ck = i & 3;
        int sck = ck ^ ((nl >> 1) & 3);
        gld16(wb + nl*32 + sck*8, &bbuf[bb][i*8]);
      }
    }
  };

  f32x4 acc[2][6];
  #pragma unroll
  for (int mi = 0; mi < 2; ++mi)
    #pragma unroll
    for (int g = 0; g < 6; ++g) acc[mi][g] = (f32x4){0.f,0.f,0.f,0.f};

  stageA(0, 0);
  stageB(0, 0, 0);
  stageB(0, 1, 1);

  for (int kb = 0; kb < 8; ++kb) {
    const int sb = kb & 1;
    #pragma unroll
    for (int tap = 0; tap < 9; ++tap) {
      const int tau = kb*9 + tap;
      if (tau == 71) waitv(0);
      else if (tap == 7 && kb < 7) waitv(myA + myB);
      else waitv(myB);
      __builtin_amdgcn_s_barrier();
      __builtin_amdgcn_sched_barrier(0);

      if (tap == 6 && kb < 7) stageA(kb+1, sb^1);
      if (tau <= 69) stageB((tau+2)/9, (tau+2)%9, (tau+2)%3);

      const int dy = tap/3, dx = tap%3;
      const int grow = h0 + rg + dy - 1;       // wave-uniform
      const bool rowok = (grow >= 0) && (grow < 32);
      const int sr = rg + dy;
      short8 a[2];
      #pragma unroll
      for (int mi = 0; mi < 2; ++mi) {
        const int cc = mi*16 + lx + dx - 1;
        const bool ok = rowok && (cc >= 0) && (cc < 32);
        const int ccc = cc < 0 ? 0 : (cc > 31 ? 31 : cc);
        short8 av = *(const short8*)&slab[sb][(sr*32 + ccc)*32 + (lk ^ ((ccc >> 1) & 3))*8];
        if (!ok) av = (short8){0,0,0,0,0,0,0,0};
        a[mi] = av;
      }
      const u16* bp = &bbuf[tau % 3][(q*96 + lx)*32 + (lk ^ ((lx >> 1) & 3))*8];
      __builtin_amdgcn_s_setprio(1);
      #pragma unroll
      for (int g = 0; g < 6; ++g) {
        short8 bv = *(const short8*)(bp + g*512);
        acc[0][g] = __builtin_amdgcn_mfma_f32_16x16x32_bf16(a[0], bv, acc[0][g], 0, 0, 0);
        acc[1][g] = __builtin_amdgcn_mfma_f32_16x16x32_bf16(a[1], bv, acc[1][g], 0, 0, 0);
      }
      __builtin_amdgcn_s_setprio(0);
    }
  }

  if constexpr (GATES) {
    const int b = img / 6;
    const int c = cb*32 + q*16 + lx;
    const float bir = b_ih[c],  bii = b_ih[256+c], bin_ = b_ih[512+c];
    const float bhr = b_hh[c],  bhi = b_hh[256+c], bhn  = b_hh[512+c];
    const float* gs0 = gsbuf + ((size_t)(b*3+0)*256 + c)*1024;
    const float* gs1 = gsbuf + ((size_t)(b*3+1)*256 + c)*1024;
    const float* gs2 = gsbuf + ((size_t)(b*3+2)*256 + c)*1024;
    const float* hp  = h_in  + ((size_t)img*256 + c)*1024;
    float*       op  = h_out + ((size_t)img*256 + c)*1024;
    const int R = h0 + rg;
    #pragma unroll
    for (int mi = 0; mi < 2; ++mi) {
      const int pix = R*32 + mi*16 + lk*4;
      float4 v0 = *(const float4*)(gs0 + pix);
      float4 v1 = *(const float4*)(gs1 + pix);
      float4 v2 = *(const float4*)(gs2 + pix);
      float4 hv = *(const float4*)(hp + pix);
      float4 o;
      #pragma unroll
      for (int r = 0; r < 4; ++r) {
        float ir  = acc[mi][0][r] + (&v0.x)[r] + bir;
        float ii  = acc[mi][1][r] + (&v1.x)[r] + bii;
        float inn = acc[mi][2][r] + (&v2.x)[r] + bin_;
        float hr  = acc[mi][3][r] + bhr;
        float hi2 = acc[mi][4][r] + bhi;
        float hn  = acc[mi][5][r] + bhn;
        float rgt = 1.f/(1.f + __expf(-(ir+hr)));
        float igt = 1.f/(1.f + __expf(-(ii+hi2)));
        float nx = inn + rgt*hn;
        nx = nx > 20.f ? 20.f : (nx < -20.f ? -20.f : nx);
        float e2 = __expf(-2.f*nx);
        float ng = (1.f - e2)/(1.f + e2);
        (&o.x)[r] = ng + igt*((&hv.x)[r] - ng);
      }
      *(float4*)(op + pix) = o;
    }
  } else {
    const int R = h0 + rg;
    #pragma unroll
    for (int g = 0; g < 6; ++g) {
      const int n = cb*NBLK + q*96 + g*16 + lx;
      float* gp = gsbuf + ((size_t)img*768 + n)*1024;
      #pragma unroll
      for (int mi = 0; mi < 2; ++mi) {
        const int pix = R*32 + mi*16 + lk*4;
        *(float4*)(gp + pix) = make_float4(acc[mi][g][0], acc[mi][g][1],
                                           acc[mi][g][2], acc[mi][g][3]);
      }
    }
  }
}

// ---------------------------------------------------------------------------
extern "C" void kernel_launch(void* const* d_in, const int* in_sizes, int n_in,
                              void* d_out, int out_size, void* d_ws, size_t ws_size,
                              hipStream_t stream) {
  const float* x    = (const float*)d_in[0];
  const float* w_ih = (const float*)d_in[1];
  const float* w_hh = (const float*)d_in[2];
  const float* b_ih = (const float*)d_in[3];
  const float* b_hh = (const float*)d_in[4];
  float* out = (float*)d_out;

  char* ws = (char*)d_ws;
  float* m0  = (float*)(ws);                 // master scratch (iter-1 output)
  u16*  xbf  = (u16*)(ws + 50331648);        // x bf16 NHWC
  u16*  sbf  = (u16*)(ws + 75497472);        // s bf16 NHWC
  float* gsb = (float*)(ws + 79691776);      // gs fp32
  u16*  wA   = (u16*)(ws + 104857600);
  u16*  wS   = (u16*)(ws + 111935488);

  k_wprep<<<2048, 256, 0, stream>>>(w_ih, w_hh, wA, wS);

  for (int it = 0; it < 3; ++it) {
    const float* src = (it == 0) ? x : (it == 1 ? out : m0);
    float* dst = (it == 1) ? m0 : out;
    k_xform<<<dim3(32, 8, 8), 256, 0, stream>>>(src, xbf, sbf);
    // s-conv: 8 batches x 4 row-blocks x 8 cb
    k_conv<1, false><<<256, 512, 0, stream>>>(sbf, wS, gsb,
                                              nullptr, nullptr, nullptr, nullptr);
    // main conv: 48 imgs x 8 row-blocks x 8 cb
    k_conv<2, true><<<3072, 512, 0, stream>>>(xbf, wA, gsb,
                                              b_ih, b_hh, src, dst);
  }
}